// Round 6
// baseline (248.365 us; speedup 1.0000x reference)
//
#include <hip/hip_runtime.h>
#include <math.h>

#define BDIM 512
#define EDIM 4096
#define KDIM 1024
#define MDIM 1024
#define LDIM 32
#define TOPK 4
#define EPSF 1e-12f

typedef __attribute__((ext_vector_type(8))) short short8;
typedef __attribute__((ext_vector_type(4))) float f32x4;

__device__ inline ushort f2bf_rn(float x) {
    union { float f; unsigned u; } v; v.f = x;
    unsigned r = (v.u + 0x7FFF + ((v.u >> 16) & 1)) >> 16;
    return (ushort)r;
}
__device__ inline float bf2f(ushort h) {
    union { unsigned u; float f; } v; v.u = ((unsigned)h) << 16;
    return v.f;
}
// fp32x8 -> (hi, lo) bf16x8. Bit-identical to the old split_all path.
__device__ inline void split8(const float4& v0, const float4& v1,
                              short8& h, short8& l)
{
    float f[8] = {v0.x, v0.y, v0.z, v0.w, v1.x, v1.y, v1.z, v1.w};
    #pragma unroll
    for (int e = 0; e < 8; ++e) {
        ushort hh = f2bf_rn(f[e]);
        h[e] = (short)hh;
        l[e] = (short)f2bf_rn(f[e] - bf2f(hh));
    }
}

// ---------------------------------------------------------------------------
// GEMM1: x_proj partials. A = x_query fp32 [512][4096], B = W_proj fp32
// [1024][4096]. In-register hi/lo bf16 split during staging (identical bits
// to the old pre-split buffers -> identical LDS content -> identical MFMA).
// 3-term split MFMA: ah*bh + ah*bl + al*bh. 64x64 tile, BK=32, 4 waves.
// Split-K=4 over blockIdx.z -> Cp1[z][512][1024].
// ---------------------------------------------------------------------------
__global__ __launch_bounds__(256)
void gemm1_kernel(const float* __restrict__ A, const float* __restrict__ B,
                  float* __restrict__ Cp)
{
    __shared__ ushort lds[4][64][40];

    const int t  = threadIdx.x;
    const int bn = blockIdx.x, bm = blockIdx.y, kz = blockIdx.z;
    const int srow = t >> 2, sg = t & 3;
    const int Kc = EDIM / 4;                     // 1024

    const float* Ap = A + (size_t)(bm * 64 + srow) * EDIM + kz * Kc + sg * 8;
    const float* Bp = B + (size_t)(bn * 64 + srow) * EDIM + kz * Kc + sg * 8;

    const int lane = t & 63, wid = t >> 6;
    const int wr = wid >> 1, wc = wid & 1;
    const int fr = lane & 15, fg = lane >> 4;

    f32x4 acc[2][2];
    #pragma unroll
    for (int i = 0; i < 2; ++i)
        #pragma unroll
        for (int j = 0; j < 2; ++j)
            acc[i][j] = (f32x4){0.f, 0.f, 0.f, 0.f};

    float4 a0 = *(const float4*)(Ap),     a1 = *(const float4*)(Ap + 4);
    float4 b0 = *(const float4*)(Bp),     b1 = *(const float4*)(Bp + 4);

    for (int k0 = 0; k0 < Kc; k0 += 32) {
        short8 ahs, als, bhs, bls;
        split8(a0, a1, ahs, als);
        split8(b0, b1, bhs, bls);
        *(short8*)(&lds[0][srow][sg * 8]) = ahs;
        *(short8*)(&lds[1][srow][sg * 8]) = als;
        *(short8*)(&lds[2][srow][sg * 8]) = bhs;
        *(short8*)(&lds[3][srow][sg * 8]) = bls;
        __syncthreads();

        if (k0 + 32 < Kc) {                       // prefetch next chunk
            a0 = *(const float4*)(Ap + k0 + 32); a1 = *(const float4*)(Ap + k0 + 36);
            b0 = *(const float4*)(Bp + k0 + 32); b1 = *(const float4*)(Bp + k0 + 36);
        }

        short8 ah[2], al[2], bh[2], bl[2];
        #pragma unroll
        for (int i = 0; i < 2; ++i) {
            ah[i] = *(const short8*)(&lds[0][wr * 32 + i * 16 + fr][fg * 8]);
            al[i] = *(const short8*)(&lds[1][wr * 32 + i * 16 + fr][fg * 8]);
            bh[i] = *(const short8*)(&lds[2][wc * 32 + i * 16 + fr][fg * 8]);
            bl[i] = *(const short8*)(&lds[3][wc * 32 + i * 16 + fr][fg * 8]);
        }
        #pragma unroll
        for (int i = 0; i < 2; ++i)
            #pragma unroll
            for (int j = 0; j < 2; ++j) {
                acc[i][j] = __builtin_amdgcn_mfma_f32_16x16x32_bf16(ah[i], bh[j], acc[i][j], 0, 0, 0);
                acc[i][j] = __builtin_amdgcn_mfma_f32_16x16x32_bf16(ah[i], bl[j], acc[i][j], 0, 0, 0);
                acc[i][j] = __builtin_amdgcn_mfma_f32_16x16x32_bf16(al[i], bh[j], acc[i][j], 0, 0, 0);
            }
        __syncthreads();
    }

    float* Cz = Cp + (size_t)kz * BDIM * KDIM;
    #pragma unroll
    for (int i = 0; i < 2; ++i)
        #pragma unroll
        for (int j = 0; j < 2; ++j)
            #pragma unroll
            for (int q = 0; q < 4; ++q) {
                int orow = bm * 64 + wr * 32 + i * 16 + (lane >> 4) * 4 + q;
                int ocol = bn * 64 + wc * 32 + j * 16 + (lane & 15);
                Cz[(size_t)orow * KDIM + ocol] = acc[i][j][q];
            }
}

// ---------------------------------------------------------------------------
// GEMM2: sim partials. A = reduce4(Cp1) (on-the-fly, z-order 0,1,2,3 per
// component -> bit-identical to the old reduce_split_norm output), B = pkeys
// fp32, both split in-register. Split-K=2 -> Cp2[z][512][1024].
// ---------------------------------------------------------------------------
__global__ __launch_bounds__(256)
void gemm2_kernel(const float* __restrict__ Cp1, const float* __restrict__ PK,
                  float* __restrict__ Cp2)
{
    __shared__ ushort lds[4][64][40];

    const int t  = threadIdx.x;
    const int bn = blockIdx.x, bm = blockIdx.y, kz = blockIdx.z;
    const int srow = t >> 2, sg = t & 3;
    const int Kc = KDIM / 2;                     // 512
    const size_t ZS = (size_t)BDIM * KDIM;       // partial stride

    const float* Ap = Cp1 + (size_t)(bm * 64 + srow) * KDIM + kz * Kc + sg * 8;
    const float* Bp = PK  + (size_t)(bn * 64 + srow) * KDIM + kz * Kc + sg * 8;

    const int lane = t & 63, wid = t >> 6;
    const int wr = wid >> 1, wc = wid & 1;
    const int fr = lane & 15, fg = lane >> 4;

    f32x4 acc[2][2];
    #pragma unroll
    for (int i = 0; i < 2; ++i)
        #pragma unroll
        for (int j = 0; j < 2; ++j)
            acc[i][j] = (f32x4){0.f, 0.f, 0.f, 0.f};

    float4 pa0[4], pa1[4], pb0, pb1;
    #pragma unroll
    for (int z = 0; z < 4; ++z) {
        pa0[z] = *(const float4*)(Ap + z * ZS);
        pa1[z] = *(const float4*)(Ap + z * ZS + 4);
    }
    pb0 = *(const float4*)(Bp);
    pb1 = *(const float4*)(Bp + 4);

    for (int k0 = 0; k0 < Kc; k0 += 32) {
        float4 s0 = pa0[0], s1 = pa1[0];
        #pragma unroll
        for (int z = 1; z < 4; ++z) {            // same z-order as old reduce
            s0.x += pa0[z].x; s0.y += pa0[z].y; s0.z += pa0[z].z; s0.w += pa0[z].w;
            s1.x += pa1[z].x; s1.y += pa1[z].y; s1.z += pa1[z].z; s1.w += pa1[z].w;
        }
        short8 ahs, als, bhs, bls;
        split8(s0, s1, ahs, als);
        split8(pb0, pb1, bhs, bls);
        *(short8*)(&lds[0][srow][sg * 8]) = ahs;
        *(short8*)(&lds[1][srow][sg * 8]) = als;
        *(short8*)(&lds[2][srow][sg * 8]) = bhs;
        *(short8*)(&lds[3][srow][sg * 8]) = bls;
        __syncthreads();

        if (k0 + 32 < Kc) {
            #pragma unroll
            for (int z = 0; z < 4; ++z) {
                pa0[z] = *(const float4*)(Ap + z * ZS + k0 + 32);
                pa1[z] = *(const float4*)(Ap + z * ZS + k0 + 36);
            }
            pb0 = *(const float4*)(Bp + k0 + 32);
            pb1 = *(const float4*)(Bp + k0 + 36);
        }

        short8 ah[2], al[2], bh[2], bl[2];
        #pragma unroll
        for (int i = 0; i < 2; ++i) {
            ah[i] = *(const short8*)(&lds[0][wr * 32 + i * 16 + fr][fg * 8]);
            al[i] = *(const short8*)(&lds[1][wr * 32 + i * 16 + fr][fg * 8]);
            bh[i] = *(const short8*)(&lds[2][wc * 32 + i * 16 + fr][fg * 8]);
            bl[i] = *(const short8*)(&lds[3][wc * 32 + i * 16 + fr][fg * 8]);
        }
        #pragma unroll
        for (int i = 0; i < 2; ++i)
            #pragma unroll
            for (int j = 0; j < 2; ++j) {
                acc[i][j] = __builtin_amdgcn_mfma_f32_16x16x32_bf16(ah[i], bh[j], acc[i][j], 0, 0, 0);
                acc[i][j] = __builtin_amdgcn_mfma_f32_16x16x32_bf16(ah[i], bl[j], acc[i][j], 0, 0, 0);
                acc[i][j] = __builtin_amdgcn_mfma_f32_16x16x32_bf16(al[i], bh[j], acc[i][j], 0, 0, 0);
            }
        __syncthreads();
    }

    float* Cz = Cp2 + (size_t)kz * BDIM * MDIM;
    #pragma unroll
    for (int i = 0; i < 2; ++i)
        #pragma unroll
        for (int j = 0; j < 2; ++j)
            #pragma unroll
            for (int q = 0; q < 4; ++q) {
                int orow = bm * 64 + wr * 32 + i * 16 + (lane >> 4) * 4 + q;
                int ocol = bn * 64 + wc * 32 + j * 16 + (lane & 15);
                Cz[(size_t)orow * MDIM + ocol] = acc[i][j][q];
            }
}

// ---------------------------------------------------------------------------
// Norms: blocks [0,1024) -> kn[m] from pkeys rows; [1024,1536) -> xn[b] from
// the z-reduced Cp1 row. Reduction orders copied verbatim from the previous
// passing kernels -> bit-identical kn/xn.
// ---------------------------------------------------------------------------
__global__ __launch_bounds__(256)
void norms_kernel(const float* __restrict__ PK, const float* __restrict__ Cp1,
                  float* __restrict__ kn, float* __restrict__ xn)
{
    const int blk = blockIdx.x, t = threadIdx.x;
    float sq;
    if (blk < MDIM) {
        float4 v = *(const float4*)(PK + (size_t)blk * KDIM + t * 4);
        sq = v.x * v.x + v.y * v.y + v.z * v.z + v.w * v.w;
    } else {
        const int b = blk - MDIM;
        const int i = b * 256 + t;
        const int n4 = BDIM * KDIM / 4;
        float4 s = ((const float4*)Cp1)[i];
        #pragma unroll
        for (int z = 1; z < 4; ++z) {
            float4 v = ((const float4*)Cp1)[(size_t)z * n4 + i];
            s.x += v.x; s.y += v.y; s.z += v.z; s.w += v.w;
        }
        sq = s.x * s.x + s.y * s.y + s.z * s.z + s.w * s.w;
    }
    #pragma unroll
    for (int off = 32; off > 0; off >>= 1) sq += __shfl_down(sq, off, 64);
    __shared__ float wsum[4];
    const int lane = t & 63, wwid = t >> 6;
    if (lane == 0) wsum[wwid] = sq;
    __syncthreads();
    if (t == 0) {
        float r = sqrtf(wsum[0] + wsum[1] + wsum[2] + wsum[3]);
        if (blk < MDIM) kn[blk] = r; else xn[blk - MDIM] = r;
    }
}

// ---------------------------------------------------------------------------
// Fused reduce(2 partials) + cosine scale + top-4 + softmax weights.
// One wave per row. Scale expression order identical to previous rounds ->
// bit-identical selection; softmax expression order identical to the old
// gather epilogue -> bit-identical weights.
// ---------------------------------------------------------------------------
__device__ inline bool tk_better(float x, int ix, float y, int iy) {
    return (x > y) || (x == y && ix < iy);
}
__device__ inline void tk_insert(float (&v)[4], int (&id)[4], float x, int m) {
    if (tk_better(x, m, v[3], id[3])) {
        v[3] = x; id[3] = m;
        if (tk_better(v[3], id[3], v[2], id[2])) {
            float tv = v[2]; int ti = id[2]; v[2] = v[3]; id[2] = id[3]; v[3] = tv; id[3] = ti;
            if (tk_better(v[2], id[2], v[1], id[1])) {
                tv = v[1]; ti = id[1]; v[1] = v[2]; id[1] = id[2]; v[2] = tv; id[2] = ti;
                if (tk_better(v[1], id[1], v[0], id[0])) {
                    tv = v[0]; ti = id[0]; v[0] = v[1]; id[0] = id[1]; v[1] = tv; id[1] = ti;
                }
            }
        }
    }
}
__global__ __launch_bounds__(64)
void topk_scale_kernel(const float* __restrict__ Cp2, const float* __restrict__ xn,
                       const float* __restrict__ kn,
                       int* __restrict__ topi, float* __restrict__ topw)
{
    const int b = blockIdx.x;
    const int lane = threadIdx.x;
    const float sb = 1.f / fmaxf(xn[b], EPSF);
    const float* r0 = Cp2 + (size_t)b * MDIM;
    const float* r1 = Cp2 + (size_t)BDIM * MDIM + (size_t)b * MDIM;

    float v[4] = {-INFINITY, -INFINITY, -INFINITY, -INFINITY};
    int id[4] = {-1, -1, -1, -1};
    for (int j = 0; j < MDIM / 64; ++j) {
        int m = j * 64 + lane;
        float s = (r0[m] + r1[m]) * sb / fmaxf(kn[m], EPSF);
        tk_insert(v, id, s, m);
    }
    for (int off = 32; off >= 1; off >>= 1) {
        float pv[4]; int pi[4];
        #pragma unroll
        for (int q = 0; q < 4; ++q) {
            pv[q] = __shfl_xor(v[q], off, 64);
            pi[q] = __shfl_xor(id[q], off, 64);
        }
        #pragma unroll
        for (int q = 0; q < 4; ++q) tk_insert(v, id, pv[q], pi[q]);
    }
    if (lane == 0) {
        const float mx = fmaxf(fmaxf(v[0], v[1]), fmaxf(v[2], v[3]));
        const float e0 = expf(v[0] - mx), e1 = expf(v[1] - mx);
        const float e2 = expf(v[2] - mx), e3 = expf(v[3] - mx);
        const float inv = 1.f / (e0 + e1 + e2 + e3);
        topw[b * 4 + 0] = e0 * inv; topw[b * 4 + 1] = e1 * inv;
        topw[b * 4 + 2] = e2 * inv; topw[b * 4 + 3] = e3 * inv;
        #pragma unroll
        for (int q = 0; q < 4; ++q) topi[b * 4 + q] = id[q];
    }
}

// ---------------------------------------------------------------------------
// Gather + weighted sum. (l, b)-major block order keeps the per-l distinct-pm
// window (~14 MB) cache-resident; non-temporal stores keep `out` from
// evicting it. Weights precomputed by topk.
// ---------------------------------------------------------------------------
__global__ __launch_bounds__(256)
void gather_out_kernel(const float* __restrict__ pm, const int* __restrict__ topi,
                       const float* __restrict__ topw, float* __restrict__ out)
{
    const int bl = blockIdx.x;
    const int b = bl & (BDIM - 1);   // (l, b)-major
    const int l = bl >> 9;

    const int j0 = topi[b * 4 + 0], j1 = topi[b * 4 + 1], j2 = topi[b * 4 + 2], j3 = topi[b * 4 + 3];
    const float w0 = topw[b * 4 + 0], w1 = topw[b * 4 + 1], w2 = topw[b * 4 + 2], w3 = topw[b * 4 + 3];

    const f32x4* p0 = (const f32x4*)(pm + ((size_t)j0 * LDIM + l) * EDIM);
    const f32x4* p1 = (const f32x4*)(pm + ((size_t)j1 * LDIM + l) * EDIM);
    const f32x4* p2 = (const f32x4*)(pm + ((size_t)j2 * LDIM + l) * EDIM);
    const f32x4* p3 = (const f32x4*)(pm + ((size_t)j3 * LDIM + l) * EDIM);
    f32x4* o = (f32x4*)(out + ((size_t)b * LDIM + l) * EDIM);

    for (int c = threadIdx.x; c < EDIM / 4; c += 256) {
        f32x4 a = p0[c], bb = p1[c], cc = p2[c], dd = p3[c];
        f32x4 r = w0 * a + w1 * bb + w2 * cc + w3 * dd;
        __builtin_nontemporal_store(r, &o[c]);
    }
}

extern "C" void kernel_launch(void* const* d_in, const int* in_sizes, int n_in,
                              void* d_out, int out_size, void* d_ws, size_t ws_size,
                              hipStream_t stream)
{
    const float* x_query = (const float*)d_in[0];      // [B, E]
    const float* W_proj  = (const float*)d_in[1];      // [K, E]
    const float* pm      = (const float*)d_in[2];      // [M, L, E]
    const float* pkeys   = (const float*)d_in[3];      // [M, K]
    float* out = (float*)d_out;                        // [B, L, E]

    // workspace layout
    char* w = (char*)d_ws;
    float* Cp1  = (float*)w; w += (size_t)4 * BDIM * KDIM * 4;   // 8 MB
    float* Cp2  = (float*)w; w += (size_t)2 * BDIM * MDIM * 4;   // 4 MB
    float* xn   = (float*)w; w += BDIM * 4;
    float* kn   = (float*)w; w += MDIM * 4;
    float* topw = (float*)w; w += BDIM * TOPK * 4;
    int*   topi = (int*)w;   w += BDIM * TOPK * 4;

    // 1. x_proj partials (fp32 inputs, in-register split, split-K=4)
    gemm1_kernel<<<dim3(KDIM / 64, BDIM / 64, 4), 256, 0, stream>>>(
        x_query, W_proj, Cp1);

    // 2. kn (pkeys rows) + xn (reduced Cp1 rows)
    norms_kernel<<<MDIM + BDIM, 256, 0, stream>>>(pkeys, Cp1, kn, xn);

    // 3. sim partials (Cp1 reduced on-the-fly, pkeys split on-the-fly, split-K=2)
    gemm2_kernel<<<dim3(MDIM / 64, BDIM / 64, 2), 256, 0, stream>>>(
        Cp1, pkeys, Cp2);

    // 4. reduce + cosine scale + top-4 + softmax weights (one wave per row)
    topk_scale_kernel<<<BDIM, 64, 0, stream>>>(Cp2, xn, kn, topi, topw);

    // 5. gather + weighted sum -> out [512,32,4096]
    gather_out_kernel<<<BDIM * LDIM, 256, 0, stream>>>(pm, topi, topw, out);
}

// Round 7
// 236.502 us; speedup vs baseline: 1.0502x; 1.0502x over previous
//
#include <hip/hip_runtime.h>
#include <math.h>

#define BDIM 512
#define EDIM 4096
#define KDIM 1024
#define MDIM 1024
#define LDIM 32
#define TOPK 4
#define EPSF 1e-12f

typedef __attribute__((ext_vector_type(8))) short short8;
typedef __attribute__((ext_vector_type(4))) float f32x4;

struct us4 { ushort x, y, z, w; };

__device__ inline ushort f2bf_rn(float x) {
    union { float f; unsigned u; } v; v.f = x;
    unsigned r = (v.u + 0x7FFF + ((v.u >> 16) & 1)) >> 16;
    return (ushort)r;
}
__device__ inline float bf2f(ushort h) {
    union { unsigned u; float f; } v; v.u = ((unsigned)h) << 16;
    return v.f;
}

// ---------------------------------------------------------------------------
// One fused split pass for all three fp32 inputs -> (hi, lo) bf16.
// Blocks [0,512) x_query, [512,1536) W_proj, [1536,1792) pkeys.
// pkeys region also computes kn[row] (bit-identical order to the original
// standalone rownorm kernel).
// ---------------------------------------------------------------------------
__global__ __launch_bounds__(256)
void split_all_kernel(const float* __restrict__ xq, const float* __restrict__ wp,
                      const float* __restrict__ pk,
                      ushort* __restrict__ xq_h, ushort* __restrict__ xq_l,
                      ushort* __restrict__ wp_h, ushort* __restrict__ wp_l,
                      ushort* __restrict__ pk_h, ushort* __restrict__ pk_l,
                      float* __restrict__ kn)
{
    const int blk = blockIdx.x;
    const int t = threadIdx.x;
    const float* src; ushort* hi; ushort* lo; int base;
    bool do_norm = false; int rowbase = 0;
    if (blk < 512)       { src = xq; hi = xq_h; lo = xq_l; base = blk * 1024; }
    else if (blk < 1536) { src = wp; hi = wp_h; lo = wp_l; base = (blk - 512) * 1024; }
    else                 { src = pk; hi = pk_h; lo = pk_l; base = (blk - 1536) * 1024;
                           do_norm = true; rowbase = (blk - 1536) * 4; }

    __shared__ float wsum[4];
    const int lane = t & 63, wwid = t >> 6;

    #pragma unroll
    for (int it = 0; it < 4; ++it) {
        const int i = base + it * 256 + t;
        float4 v = ((const float4*)src)[i];
        us4 h, l;
        h.x = f2bf_rn(v.x); l.x = f2bf_rn(v.x - bf2f(h.x));
        h.y = f2bf_rn(v.y); l.y = f2bf_rn(v.y - bf2f(h.y));
        h.z = f2bf_rn(v.z); l.z = f2bf_rn(v.z - bf2f(h.z));
        h.w = f2bf_rn(v.w); l.w = f2bf_rn(v.w - bf2f(h.w));
        ((us4*)hi)[i] = h;
        ((us4*)lo)[i] = l;

        if (do_norm) {
            float sq = v.x * v.x + v.y * v.y + v.z * v.z + v.w * v.w;
            #pragma unroll
            for (int off = 32; off > 0; off >>= 1) sq += __shfl_down(sq, off, 64);
            __syncthreads();                    // WAR vs previous iteration's wsum
            if (lane == 0) wsum[wwid] = sq;
            __syncthreads();
            if (t == 0)
                kn[rowbase + it] = sqrtf(wsum[0] + wsum[1] + wsum[2] + wsum[3]);
        }
    }
}

// ---------------------------------------------------------------------------
// GEMM1: x_proj partials from pre-split bf16. 64(M) x 128(N) tile, BK=32,
// 256 threads = 4 waves (2 wr x 2 wc), each wave 32x64 = 2x4 16x16x32 frags.
// Split-K=4 over blockIdx.z -> Cp1[z][512][1024]. Grid (8,8,4) = 256 blocks:
// halves A re-reads vs the 64x64 tiling (268->201 MB L2 staging traffic) and
// improves LDS-read:MFMA from 8:12 to 12:24 per wave per k-step.
// Per-element accumulation sequence (split-K chunks, BK order, hh/hl/lh term
// order) identical to the 64x64 version -> bit-identical Cp1.
// ---------------------------------------------------------------------------
__global__ __launch_bounds__(256)
void gemm1_kernel(const ushort* __restrict__ Ah, const ushort* __restrict__ Al,
                  const ushort* __restrict__ Bh, const ushort* __restrict__ Bl,
                  float* __restrict__ Cp)
{
    __shared__ ushort ldsA[2][64][40];
    __shared__ ushort ldsB[2][128][40];

    const int t  = threadIdx.x;
    const int bn = blockIdx.x, bm = blockIdx.y, kz = blockIdx.z;
    const int srow = t >> 2, sg = t & 3;
    const int Kc = EDIM / 4;                     // 1024

    const size_t aoff  = (size_t)(bm * 64 + srow) * EDIM + kz * Kc + sg * 8;
    const size_t boff0 = (size_t)(bn * 128 + srow) * EDIM + kz * Kc + sg * 8;
    const size_t boff1 = (size_t)(bn * 128 + 64 + srow) * EDIM + kz * Kc + sg * 8;

    const int lane = t & 63, wid = t >> 6;
    const int wr = wid >> 1, wc = wid & 1;
    const int fr = lane & 15, fg = lane >> 4;

    f32x4 acc[2][4];
    #pragma unroll
    for (int i = 0; i < 2; ++i)
        #pragma unroll
        for (int j = 0; j < 4; ++j)
            acc[i][j] = (f32x4){0.f, 0.f, 0.f, 0.f};

    short8 pAh = *(const short8*)(Ah + aoff);
    short8 pAl = *(const short8*)(Al + aoff);
    short8 pBh0 = *(const short8*)(Bh + boff0);
    short8 pBl0 = *(const short8*)(Bl + boff0);
    short8 pBh1 = *(const short8*)(Bh + boff1);
    short8 pBl1 = *(const short8*)(Bl + boff1);

    for (int k0 = 0; k0 < Kc; k0 += 32) {
        *(short8*)(&ldsA[0][srow][sg * 8]) = pAh;
        *(short8*)(&ldsA[1][srow][sg * 8]) = pAl;
        *(short8*)(&ldsB[0][srow][sg * 8]) = pBh0;
        *(short8*)(&ldsB[1][srow][sg * 8]) = pBl0;
        *(short8*)(&ldsB[0][64 + srow][sg * 8]) = pBh1;
        *(short8*)(&ldsB[1][64 + srow][sg * 8]) = pBl1;
        __syncthreads();

        if (k0 + 32 < Kc) {                       // prefetch next chunk
            pAh = *(const short8*)(Ah + aoff + k0 + 32);
            pAl = *(const short8*)(Al + aoff + k0 + 32);
            pBh0 = *(const short8*)(Bh + boff0 + k0 + 32);
            pBl0 = *(const short8*)(Bl + boff0 + k0 + 32);
            pBh1 = *(const short8*)(Bh + boff1 + k0 + 32);
            pBl1 = *(const short8*)(Bl + boff1 + k0 + 32);
        }

        short8 ah[2], al[2], bh[4], bl[4];
        #pragma unroll
        for (int i = 0; i < 2; ++i) {
            ah[i] = *(const short8*)(&ldsA[0][wr * 32 + i * 16 + fr][fg * 8]);
            al[i] = *(const short8*)(&ldsA[1][wr * 32 + i * 16 + fr][fg * 8]);
        }
        #pragma unroll
        for (int j = 0; j < 4; ++j) {
            bh[j] = *(const short8*)(&ldsB[0][wc * 64 + j * 16 + fr][fg * 8]);
            bl[j] = *(const short8*)(&ldsB[1][wc * 64 + j * 16 + fr][fg * 8]);
        }
        #pragma unroll
        for (int i = 0; i < 2; ++i)
            #pragma unroll
            for (int j = 0; j < 4; ++j) {
                acc[i][j] = __builtin_amdgcn_mfma_f32_16x16x32_bf16(ah[i], bh[j], acc[i][j], 0, 0, 0);
                acc[i][j] = __builtin_amdgcn_mfma_f32_16x16x32_bf16(ah[i], bl[j], acc[i][j], 0, 0, 0);
                acc[i][j] = __builtin_amdgcn_mfma_f32_16x16x32_bf16(al[i], bh[j], acc[i][j], 0, 0, 0);
            }
        __syncthreads();
    }

    float* Cz = Cp + (size_t)kz * BDIM * KDIM;
    #pragma unroll
    for (int i = 0; i < 2; ++i)
        #pragma unroll
        for (int j = 0; j < 4; ++j)
            #pragma unroll
            for (int q = 0; q < 4; ++q) {
                int orow = bm * 64 + wr * 32 + i * 16 + (lane >> 4) * 4 + q;
                int ocol = bn * 128 + wc * 64 + j * 16 + (lane & 15);
                Cz[(size_t)orow * KDIM + ocol] = acc[i][j][q];
            }
}

// ---------------------------------------------------------------------------
// GEMM2 (sim partials): 64x64 tile version on pre-split inputs, unchanged
// from the round-5 passing kernel.
// ---------------------------------------------------------------------------
__global__ __launch_bounds__(256)
void gemm_mfma_split(const ushort* __restrict__ Ah, const ushort* __restrict__ Al,
                     const ushort* __restrict__ Bh, const ushort* __restrict__ Bl,
                     float* __restrict__ Cp, int M, int N, int K, int Kchunk)
{
    __shared__ ushort lds[4][64][40];

    const int t  = threadIdx.x;
    const int bn = blockIdx.x, bm = blockIdx.y, kz = blockIdx.z;

    const int srow = t >> 2, sg = t & 3;
    const size_t aoff = (size_t)(bm * 64 + srow) * K + sg * 8 + (size_t)kz * Kchunk;
    const size_t boff = (size_t)(bn * 64 + srow) * K + sg * 8 + (size_t)kz * Kchunk;

    const int lane = t & 63, wid = t >> 6;
    const int wr = wid >> 1, wc = wid & 1;
    const int fr = lane & 15, fg = lane >> 4;

    f32x4 acc[2][2];
    #pragma unroll
    for (int i = 0; i < 2; ++i)
        #pragma unroll
        for (int j = 0; j < 2; ++j)
            acc[i][j] = (f32x4){0.f, 0.f, 0.f, 0.f};

    short8 pA0 = *(const short8*)(Ah + aoff);
    short8 pA1 = *(const short8*)(Al + aoff);
    short8 pB0 = *(const short8*)(Bh + boff);
    short8 pB1 = *(const short8*)(Bl + boff);

    for (int k0 = 0; k0 < Kchunk; k0 += 32) {
        *(short8*)(&lds[0][srow][sg * 8]) = pA0;
        *(short8*)(&lds[1][srow][sg * 8]) = pA1;
        *(short8*)(&lds[2][srow][sg * 8]) = pB0;
        *(short8*)(&lds[3][srow][sg * 8]) = pB1;
        __syncthreads();

        if (k0 + 32 < Kchunk) {
            pA0 = *(const short8*)(Ah + aoff + k0 + 32);
            pA1 = *(const short8*)(Al + aoff + k0 + 32);
            pB0 = *(const short8*)(Bh + boff + k0 + 32);
            pB1 = *(const short8*)(Bl + boff + k0 + 32);
        }

        short8 ah[2], al[2], bh[2], bl[2];
        #pragma unroll
        for (int i = 0; i < 2; ++i) {
            ah[i] = *(const short8*)(&lds[0][wr * 32 + i * 16 + fr][fg * 8]);
            al[i] = *(const short8*)(&lds[1][wr * 32 + i * 16 + fr][fg * 8]);
            bh[i] = *(const short8*)(&lds[2][wc * 32 + i * 16 + fr][fg * 8]);
            bl[i] = *(const short8*)(&lds[3][wc * 32 + i * 16 + fr][fg * 8]);
        }
        #pragma unroll
        for (int i = 0; i < 2; ++i)
            #pragma unroll
            for (int j = 0; j < 2; ++j) {
                acc[i][j] = __builtin_amdgcn_mfma_f32_16x16x32_bf16(ah[i], bh[j], acc[i][j], 0, 0, 0);
                acc[i][j] = __builtin_amdgcn_mfma_f32_16x16x32_bf16(ah[i], bl[j], acc[i][j], 0, 0, 0);
                acc[i][j] = __builtin_amdgcn_mfma_f32_16x16x32_bf16(al[i], bh[j], acc[i][j], 0, 0, 0);
            }
        __syncthreads();
    }

    float* Cz = Cp + (size_t)kz * M * N;
    #pragma unroll
    for (int i = 0; i < 2; ++i)
        #pragma unroll
        for (int j = 0; j < 2; ++j)
            #pragma unroll
            for (int q = 0; q < 4; ++q) {
                int orow = bm * 64 + wr * 32 + i * 16 + (lane >> 4) * 4 + q;
                int ocol = bn * 64 + wc * 32 + j * 16 + (lane & 15);
                Cz[(size_t)orow * N + ocol] = acc[i][j][q];
            }
}

// ---------------------------------------------------------------------------
// Fused: reduce split-K=4 partials of x_proj + row L2-norm + hi/lo split.
// One block per row b. Unchanged from round 5 (bit-identical).
// ---------------------------------------------------------------------------
__global__ __launch_bounds__(256)
void reduce_split_norm_kernel(const float* __restrict__ Cp,
                              ushort* __restrict__ xh, ushort* __restrict__ xl,
                              float* __restrict__ xn)
{
    const int b = blockIdx.x;
    const int i = b * 256 + threadIdx.x;
    const int n4 = BDIM * KDIM / 4;

    float4 s = ((const float4*)Cp)[i];
    #pragma unroll
    for (int z = 1; z < 4; ++z) {
        float4 v = ((const float4*)Cp)[(size_t)z * n4 + i];
        s.x += v.x; s.y += v.y; s.z += v.z; s.w += v.w;
    }

    us4 h, l;
    h.x = f2bf_rn(s.x); l.x = f2bf_rn(s.x - bf2f(h.x));
    h.y = f2bf_rn(s.y); l.y = f2bf_rn(s.y - bf2f(h.y));
    h.z = f2bf_rn(s.z); l.z = f2bf_rn(s.z - bf2f(h.z));
    h.w = f2bf_rn(s.w); l.w = f2bf_rn(s.w - bf2f(h.w));
    ((us4*)xh)[i] = h;
    ((us4*)xl)[i] = l;

    float sq = s.x * s.x + s.y * s.y + s.z * s.z + s.w * s.w;
    #pragma unroll
    for (int off = 32; off > 0; off >>= 1) sq += __shfl_down(sq, off, 64);
    __shared__ float wsum[4];
    const int lane = threadIdx.x & 63, wwid = threadIdx.x >> 6;
    if (lane == 0) wsum[wwid] = sq;
    __syncthreads();
    if (threadIdx.x == 0)
        xn[b] = sqrtf(wsum[0] + wsum[1] + wsum[2] + wsum[3]);
}

// ---------------------------------------------------------------------------
// Fused reduce(2 partials) + cosine scale + top-4 + softmax weights.
// One wave per row. Unchanged from round 5 (bit-identical).
// ---------------------------------------------------------------------------
__device__ inline bool tk_better(float x, int ix, float y, int iy) {
    return (x > y) || (x == y && ix < iy);
}
__device__ inline void tk_insert(float (&v)[4], int (&id)[4], float x, int m) {
    if (tk_better(x, m, v[3], id[3])) {
        v[3] = x; id[3] = m;
        if (tk_better(v[3], id[3], v[2], id[2])) {
            float tv = v[2]; int ti = id[2]; v[2] = v[3]; id[2] = id[3]; v[3] = tv; id[3] = ti;
            if (tk_better(v[2], id[2], v[1], id[1])) {
                tv = v[1]; ti = id[1]; v[1] = v[2]; id[1] = id[2]; v[2] = tv; id[2] = ti;
                if (tk_better(v[1], id[1], v[0], id[0])) {
                    tv = v[0]; ti = id[0]; v[0] = v[1]; id[0] = id[1]; v[1] = tv; id[1] = ti;
                }
            }
        }
    }
}
__global__ __launch_bounds__(64)
void topk_scale_kernel(const float* __restrict__ Cp2, const float* __restrict__ xn,
                       const float* __restrict__ kn,
                       int* __restrict__ topi, float* __restrict__ topw)
{
    const int b = blockIdx.x;
    const int lane = threadIdx.x;
    const float sb = 1.f / fmaxf(xn[b], EPSF);
    const float* r0 = Cp2 + (size_t)b * MDIM;
    const float* r1 = Cp2 + (size_t)BDIM * MDIM + (size_t)b * MDIM;

    float v[4] = {-INFINITY, -INFINITY, -INFINITY, -INFINITY};
    int id[4] = {-1, -1, -1, -1};
    for (int j = 0; j < MDIM / 64; ++j) {
        int m = j * 64 + lane;
        float s = (r0[m] + r1[m]) * sb / fmaxf(kn[m], EPSF);
        tk_insert(v, id, s, m);
    }
    for (int off = 32; off >= 1; off >>= 1) {
        float pv[4]; int pi[4];
        #pragma unroll
        for (int q = 0; q < 4; ++q) {
            pv[q] = __shfl_xor(v[q], off, 64);
            pi[q] = __shfl_xor(id[q], off, 64);
        }
        #pragma unroll
        for (int q = 0; q < 4; ++q) tk_insert(v, id, pv[q], pi[q]);
    }
    if (lane == 0) {
        const float mx = fmaxf(fmaxf(v[0], v[1]), fmaxf(v[2], v[3]));
        const float e0 = expf(v[0] - mx), e1 = expf(v[1] - mx);
        const float e2 = expf(v[2] - mx), e3 = expf(v[3] - mx);
        const float inv = 1.f / (e0 + e1 + e2 + e3);
        topw[b * 4 + 0] = e0 * inv; topw[b * 4 + 1] = e1 * inv;
        topw[b * 4 + 2] = e2 * inv; topw[b * 4 + 3] = e3 * inv;
        #pragma unroll
        for (int q = 0; q < 4; ++q) topi[b * 4 + q] = id[q];
    }
}

// ---------------------------------------------------------------------------
// Gather + weighted sum. (l, b)-major + non-temporal stores. Unchanged.
// ---------------------------------------------------------------------------
__global__ __launch_bounds__(256)
void gather_out_kernel(const float* __restrict__ pm, const int* __restrict__ topi,
                       const float* __restrict__ topw, float* __restrict__ out)
{
    const int bl = blockIdx.x;
    const int b = bl & (BDIM - 1);   // (l, b)-major
    const int l = bl >> 9;

    const int j0 = topi[b * 4 + 0], j1 = topi[b * 4 + 1], j2 = topi[b * 4 + 2], j3 = topi[b * 4 + 3];
    const float w0 = topw[b * 4 + 0], w1 = topw[b * 4 + 1], w2 = topw[b * 4 + 2], w3 = topw[b * 4 + 3];

    const f32x4* p0 = (const f32x4*)(pm + ((size_t)j0 * LDIM + l) * EDIM);
    const f32x4* p1 = (const f32x4*)(pm + ((size_t)j1 * LDIM + l) * EDIM);
    const f32x4* p2 = (const f32x4*)(pm + ((size_t)j2 * LDIM + l) * EDIM);
    const f32x4* p3 = (const f32x4*)(pm + ((size_t)j3 * LDIM + l) * EDIM);
    f32x4* o = (f32x4*)(out + ((size_t)b * LDIM + l) * EDIM);

    for (int c = threadIdx.x; c < EDIM / 4; c += 256) {
        f32x4 a = p0[c], bb = p1[c], cc = p2[c], dd = p3[c];
        f32x4 r = w0 * a + w1 * bb + w2 * cc + w3 * dd;
        __builtin_nontemporal_store(r, &o[c]);
    }
}

extern "C" void kernel_launch(void* const* d_in, const int* in_sizes, int n_in,
                              void* d_out, int out_size, void* d_ws, size_t ws_size,
                              hipStream_t stream)
{
    const float* x_query = (const float*)d_in[0];      // [B, E]
    const float* W_proj  = (const float*)d_in[1];      // [K, E]
    const float* pm      = (const float*)d_in[2];      // [M, L, E]
    const float* pkeys   = (const float*)d_in[3];      // [M, K]
    float* out = (float*)d_out;                        // [B, L, E]

    // workspace layout
    char* w = (char*)d_ws;
    ushort* xq_h = (ushort*)w; w += (size_t)BDIM * EDIM * 2;
    ushort* xq_l = (ushort*)w; w += (size_t)BDIM * EDIM * 2;
    ushort* wp_h = (ushort*)w; w += (size_t)KDIM * EDIM * 2;
    ushort* wp_l = (ushort*)w; w += (size_t)KDIM * EDIM * 2;
    ushort* pk_h = (ushort*)w; w += (size_t)MDIM * KDIM * 2;
    ushort* pk_l = (ushort*)w; w += (size_t)MDIM * KDIM * 2;
    ushort* xp_h = (ushort*)w; w += (size_t)BDIM * KDIM * 2;
    ushort* xp_l = (ushort*)w; w += (size_t)BDIM * KDIM * 2;
    float* Cp1  = (float*)w; w += (size_t)4 * BDIM * KDIM * 4;
    float* Cp2  = (float*)w; w += (size_t)2 * BDIM * MDIM * 4;
    float* xn   = (float*)w; w += BDIM * 4;
    float* kn   = (float*)w; w += MDIM * 4;
    float* topw = (float*)w; w += BDIM * TOPK * 4;
    int*   topi = (int*)w;   w += BDIM * TOPK * 4;

    // 1. split all three fp32 inputs to hi/lo bf16 + pkeys row norms
    split_all_kernel<<<1792, 256, 0, stream>>>(
        x_query, W_proj, pkeys, xq_h, xq_l, wp_h, wp_l, pk_h, pk_l, kn);

    // 2. x_proj partials (64x128 tile, split-K=4)
    gemm1_kernel<<<dim3(KDIM / 128, BDIM / 64, 4), 256, 0, stream>>>(
        xq_h, xq_l, wp_h, wp_l, Cp1);

    // 3. fused reduce + rownorm + split of x_proj (one block per row)
    reduce_split_norm_kernel<<<BDIM, 256, 0, stream>>>(Cp1, xp_h, xp_l, xn);

    // 4. sim partials (split-K=2)
    gemm_mfma_split<<<dim3(MDIM / 64, BDIM / 64, 2), 256, 0, stream>>>(
        xp_h, xp_l, pk_h, pk_l, Cp2, BDIM, MDIM, KDIM, KDIM / 2);

    // 5. fused reduce + cosine scale + top-4 + softmax weights (one wave per row)
    topk_scale_kernel<<<BDIM, 64, 0, stream>>>(Cp2, xn, kn, topi, topw);

    // 6. gather + weighted sum -> out [512,32,4096]
    gather_out_kernel<<<BDIM * LDIM, 256, 0, stream>>>(pm, topi, topw, out);
}

// Round 8
// 234.627 us; speedup vs baseline: 1.0586x; 1.0080x over previous
//
#include <hip/hip_runtime.h>
#include <math.h>

#define BDIM 512
#define EDIM 4096
#define KDIM 1024
#define MDIM 1024
#define LDIM 32
#define TOPK 4
#define EPSF 1e-12f

typedef __attribute__((ext_vector_type(8))) short short8;
typedef __attribute__((ext_vector_type(4))) float f32x4;

struct us4 { ushort x, y, z, w; };

__device__ inline ushort f2bf_rn(float x) {
    union { float f; unsigned u; } v; v.f = x;
    unsigned r = (v.u + 0x7FFF + ((v.u >> 16) & 1)) >> 16;
    return (ushort)r;
}
__device__ inline float bf2f(ushort h) {
    union { unsigned u; float f; } v; v.u = ((unsigned)h) << 16;
    return v.f;
}

// ---------------------------------------------------------------------------
// One fused split pass for all three fp32 inputs -> (hi, lo) bf16.
// Blocks [0,512) x_query, [512,1536) W_proj, [1536,1792) pkeys.
// pkeys region also computes kn[row] (bit-identical order to the original
// standalone rownorm kernel).
// ---------------------------------------------------------------------------
__global__ __launch_bounds__(256)
void split_all_kernel(const float* __restrict__ xq, const float* __restrict__ wp,
                      const float* __restrict__ pk,
                      ushort* __restrict__ xq_h, ushort* __restrict__ xq_l,
                      ushort* __restrict__ wp_h, ushort* __restrict__ wp_l,
                      ushort* __restrict__ pk_h, ushort* __restrict__ pk_l,
                      float* __restrict__ kn)
{
    const int blk = blockIdx.x;
    const int t = threadIdx.x;
    const float* src; ushort* hi; ushort* lo; int base;
    bool do_norm = false; int rowbase = 0;
    if (blk < 512)       { src = xq; hi = xq_h; lo = xq_l; base = blk * 1024; }
    else if (blk < 1536) { src = wp; hi = wp_h; lo = wp_l; base = (blk - 512) * 1024; }
    else                 { src = pk; hi = pk_h; lo = pk_l; base = (blk - 1536) * 1024;
                           do_norm = true; rowbase = (blk - 1536) * 4; }

    __shared__ float wsum[4];
    const int lane = t & 63, wwid = t >> 6;

    #pragma unroll
    for (int it = 0; it < 4; ++it) {
        const int i = base + it * 256 + t;
        float4 v = ((const float4*)src)[i];
        us4 h, l;
        h.x = f2bf_rn(v.x); l.x = f2bf_rn(v.x - bf2f(h.x));
        h.y = f2bf_rn(v.y); l.y = f2bf_rn(v.y - bf2f(h.y));
        h.z = f2bf_rn(v.z); l.z = f2bf_rn(v.z - bf2f(h.z));
        h.w = f2bf_rn(v.w); l.w = f2bf_rn(v.w - bf2f(h.w));
        ((us4*)hi)[i] = h;
        ((us4*)lo)[i] = l;

        if (do_norm) {
            float sq = v.x * v.x + v.y * v.y + v.z * v.z + v.w * v.w;
            #pragma unroll
            for (int off = 32; off > 0; off >>= 1) sq += __shfl_down(sq, off, 64);
            __syncthreads();                    // WAR vs previous iteration's wsum
            if (lane == 0) wsum[wwid] = sq;
            __syncthreads();
            if (t == 0)
                kn[rowbase + it] = sqrtf(wsum[0] + wsum[1] + wsum[2] + wsum[3]);
        }
    }
}

// ---------------------------------------------------------------------------
// GEMM1: x_proj partials from pre-split bf16. 64(M) x 128(N) tile, BK=32,
// 4 waves each 32x64 (2x4 16x16x32 frags). Split-K=4 -> Cp1[z][512][1024].
// Grid (8,8,4) = 256 blocks = 1 block/CU -> no cross-block overlap, so LDS is
// DOUBLE-BUFFERED: one barrier per k-step; global prefetch + ds_write of
// buf p^1 overlap MFMA on buf p. Scheduling-only change -> bit-identical Cp1.
// ---------------------------------------------------------------------------
__global__ __launch_bounds__(256)
void gemm1_kernel(const ushort* __restrict__ Ah, const ushort* __restrict__ Al,
                  const ushort* __restrict__ Bh, const ushort* __restrict__ Bl,
                  float* __restrict__ Cp)
{
    __shared__ ushort ldsA[2][2][64][40];    // [buf][hi/lo][row][col]
    __shared__ ushort ldsB[2][2][128][40];

    const int t  = threadIdx.x;
    const int bn = blockIdx.x, bm = blockIdx.y, kz = blockIdx.z;
    const int srow = t >> 2, sg = t & 3;
    const int Kc = EDIM / 4;                 // 1024

    const size_t aoff  = (size_t)(bm * 64 + srow) * EDIM + kz * Kc + sg * 8;
    const size_t boff0 = (size_t)(bn * 128 + srow) * EDIM + kz * Kc + sg * 8;
    const size_t boff1 = (size_t)(bn * 128 + 64 + srow) * EDIM + kz * Kc + sg * 8;

    const int lane = t & 63, wid = t >> 6;
    const int wr = wid >> 1, wc = wid & 1;
    const int fr = lane & 15, fg = lane >> 4;

    f32x4 acc[2][4];
    #pragma unroll
    for (int i = 0; i < 2; ++i)
        #pragma unroll
        for (int j = 0; j < 4; ++j)
            acc[i][j] = (f32x4){0.f, 0.f, 0.f, 0.f};

    short8 pAh = *(const short8*)(Ah + aoff);
    short8 pAl = *(const short8*)(Al + aoff);
    short8 pBh0 = *(const short8*)(Bh + boff0);
    short8 pBl0 = *(const short8*)(Bl + boff0);
    short8 pBh1 = *(const short8*)(Bh + boff1);
    short8 pBl1 = *(const short8*)(Bl + boff1);

    *(short8*)(&ldsA[0][0][srow][sg * 8]) = pAh;
    *(short8*)(&ldsA[0][1][srow][sg * 8]) = pAl;
    *(short8*)(&ldsB[0][0][srow][sg * 8]) = pBh0;
    *(short8*)(&ldsB[0][1][srow][sg * 8]) = pBl0;
    *(short8*)(&ldsB[0][0][64 + srow][sg * 8]) = pBh1;
    *(short8*)(&ldsB[0][1][64 + srow][sg * 8]) = pBl1;

    int p = 0;
    for (int k0 = 0; k0 < Kc; k0 += 32) {
        const bool more = (k0 + 32 < Kc);
        if (more) {                          // issue next-chunk global loads
            pAh = *(const short8*)(Ah + aoff + k0 + 32);
            pAl = *(const short8*)(Al + aoff + k0 + 32);
            pBh0 = *(const short8*)(Bh + boff0 + k0 + 32);
            pBl0 = *(const short8*)(Bl + boff0 + k0 + 32);
            pBh1 = *(const short8*)(Bh + boff1 + k0 + 32);
            pBl1 = *(const short8*)(Bl + boff1 + k0 + 32);
        }
        __syncthreads();                     // buf[p] writes visible

        short8 ah[2], al[2], bh[4], bl[4];
        #pragma unroll
        for (int i = 0; i < 2; ++i) {
            ah[i] = *(const short8*)(&ldsA[p][0][wr * 32 + i * 16 + fr][fg * 8]);
            al[i] = *(const short8*)(&ldsA[p][1][wr * 32 + i * 16 + fr][fg * 8]);
        }
        #pragma unroll
        for (int j = 0; j < 4; ++j) {
            bh[j] = *(const short8*)(&ldsB[p][0][wc * 64 + j * 16 + fr][fg * 8]);
            bl[j] = *(const short8*)(&ldsB[p][1][wc * 64 + j * 16 + fr][fg * 8]);
        }
        #pragma unroll
        for (int i = 0; i < 2; ++i)
            #pragma unroll
            for (int j = 0; j < 4; ++j) {
                acc[i][j] = __builtin_amdgcn_mfma_f32_16x16x32_bf16(ah[i], bh[j], acc[i][j], 0, 0, 0);
                acc[i][j] = __builtin_amdgcn_mfma_f32_16x16x32_bf16(ah[i], bl[j], acc[i][j], 0, 0, 0);
                acc[i][j] = __builtin_amdgcn_mfma_f32_16x16x32_bf16(al[i], bh[j], acc[i][j], 0, 0, 0);
            }

        if (more) {                          // write next chunk to buf[p^1]
            *(short8*)(&ldsA[p ^ 1][0][srow][sg * 8]) = pAh;
            *(short8*)(&ldsA[p ^ 1][1][srow][sg * 8]) = pAl;
            *(short8*)(&ldsB[p ^ 1][0][srow][sg * 8]) = pBh0;
            *(short8*)(&ldsB[p ^ 1][1][srow][sg * 8]) = pBl0;
            *(short8*)(&ldsB[p ^ 1][0][64 + srow][sg * 8]) = pBh1;
            *(short8*)(&ldsB[p ^ 1][1][64 + srow][sg * 8]) = pBl1;
        }
        p ^= 1;
    }

    float* Cz = Cp + (size_t)kz * BDIM * KDIM;
    #pragma unroll
    for (int i = 0; i < 2; ++i)
        #pragma unroll
        for (int j = 0; j < 4; ++j)
            #pragma unroll
            for (int q = 0; q < 4; ++q) {
                int orow = bm * 64 + wr * 32 + i * 16 + (lane >> 4) * 4 + q;
                int ocol = bn * 128 + wc * 64 + j * 16 + (lane & 15);
                Cz[(size_t)orow * KDIM + ocol] = acc[i][j][q];
            }
}

// ---------------------------------------------------------------------------
// GEMM2 (sim partials): 64x64 tile on pre-split inputs, split-K=2, now with
// the same LDS double-buffering (grid 256 = 1 block/CU). Bit-identical math.
// ---------------------------------------------------------------------------
__global__ __launch_bounds__(256)
void gemm2_kernel(const ushort* __restrict__ Ah, const ushort* __restrict__ Al,
                  const ushort* __restrict__ Bh, const ushort* __restrict__ Bl,
                  float* __restrict__ Cp)
{
    __shared__ ushort lds[2][4][64][40];     // [buf][Ah/Al/Bh/Bl][row][col]

    const int t  = threadIdx.x;
    const int bn = blockIdx.x, bm = blockIdx.y, kz = blockIdx.z;
    const int srow = t >> 2, sg = t & 3;
    const int Kc = KDIM / 2;                 // 512

    const size_t aoff = (size_t)(bm * 64 + srow) * KDIM + kz * Kc + sg * 8;
    const size_t boff = (size_t)(bn * 64 + srow) * KDIM + kz * Kc + sg * 8;

    const int lane = t & 63, wid = t >> 6;
    const int wr = wid >> 1, wc = wid & 1;
    const int fr = lane & 15, fg = lane >> 4;

    f32x4 acc[2][2];
    #pragma unroll
    for (int i = 0; i < 2; ++i)
        #pragma unroll
        for (int j = 0; j < 2; ++j)
            acc[i][j] = (f32x4){0.f, 0.f, 0.f, 0.f};

    short8 pA0 = *(const short8*)(Ah + aoff);
    short8 pA1 = *(const short8*)(Al + aoff);
    short8 pB0 = *(const short8*)(Bh + boff);
    short8 pB1 = *(const short8*)(Bl + boff);

    *(short8*)(&lds[0][0][srow][sg * 8]) = pA0;
    *(short8*)(&lds[0][1][srow][sg * 8]) = pA1;
    *(short8*)(&lds[0][2][srow][sg * 8]) = pB0;
    *(short8*)(&lds[0][3][srow][sg * 8]) = pB1;

    int p = 0;
    for (int k0 = 0; k0 < Kc; k0 += 32) {
        const bool more = (k0 + 32 < Kc);
        if (more) {
            pA0 = *(const short8*)(Ah + aoff + k0 + 32);
            pA1 = *(const short8*)(Al + aoff + k0 + 32);
            pB0 = *(const short8*)(Bh + boff + k0 + 32);
            pB1 = *(const short8*)(Bl + boff + k0 + 32);
        }
        __syncthreads();

        short8 ah[2], al[2], bh[2], bl[2];
        #pragma unroll
        for (int i = 0; i < 2; ++i) {
            ah[i] = *(const short8*)(&lds[p][0][wr * 32 + i * 16 + fr][fg * 8]);
            al[i] = *(const short8*)(&lds[p][1][wr * 32 + i * 16 + fr][fg * 8]);
            bh[i] = *(const short8*)(&lds[p][2][wc * 32 + i * 16 + fr][fg * 8]);
            bl[i] = *(const short8*)(&lds[p][3][wc * 32 + i * 16 + fr][fg * 8]);
        }
        #pragma unroll
        for (int i = 0; i < 2; ++i)
            #pragma unroll
            for (int j = 0; j < 2; ++j) {
                acc[i][j] = __builtin_amdgcn_mfma_f32_16x16x32_bf16(ah[i], bh[j], acc[i][j], 0, 0, 0);
                acc[i][j] = __builtin_amdgcn_mfma_f32_16x16x32_bf16(ah[i], bl[j], acc[i][j], 0, 0, 0);
                acc[i][j] = __builtin_amdgcn_mfma_f32_16x16x32_bf16(al[i], bh[j], acc[i][j], 0, 0, 0);
            }

        if (more) {
            *(short8*)(&lds[p ^ 1][0][srow][sg * 8]) = pA0;
            *(short8*)(&lds[p ^ 1][1][srow][sg * 8]) = pA1;
            *(short8*)(&lds[p ^ 1][2][srow][sg * 8]) = pB0;
            *(short8*)(&lds[p ^ 1][3][srow][sg * 8]) = pB1;
        }
        p ^= 1;
    }

    float* Cz = Cp + (size_t)kz * BDIM * MDIM;
    #pragma unroll
    for (int i = 0; i < 2; ++i)
        #pragma unroll
        for (int j = 0; j < 2; ++j)
            #pragma unroll
            for (int q = 0; q < 4; ++q) {
                int orow = bm * 64 + wr * 32 + i * 16 + (lane >> 4) * 4 + q;
                int ocol = bn * 64 + wc * 32 + j * 16 + (lane & 15);
                Cz[(size_t)orow * MDIM + ocol] = acc[i][j][q];
            }
}

// ---------------------------------------------------------------------------
// Fused: reduce split-K=4 partials of x_proj + row L2-norm + hi/lo split.
// One block per row b. Unchanged (bit-identical).
// ---------------------------------------------------------------------------
__global__ __launch_bounds__(256)
void reduce_split_norm_kernel(const float* __restrict__ Cp,
                              ushort* __restrict__ xh, ushort* __restrict__ xl,
                              float* __restrict__ xn)
{
    const int b = blockIdx.x;
    const int i = b * 256 + threadIdx.x;
    const int n4 = BDIM * KDIM / 4;

    float4 s = ((const float4*)Cp)[i];
    #pragma unroll
    for (int z = 1; z < 4; ++z) {
        float4 v = ((const float4*)Cp)[(size_t)z * n4 + i];
        s.x += v.x; s.y += v.y; s.z += v.z; s.w += v.w;
    }

    us4 h, l;
    h.x = f2bf_rn(s.x); l.x = f2bf_rn(s.x - bf2f(h.x));
    h.y = f2bf_rn(s.y); l.y = f2bf_rn(s.y - bf2f(h.y));
    h.z = f2bf_rn(s.z); l.z = f2bf_rn(s.z - bf2f(h.z));
    h.w = f2bf_rn(s.w); l.w = f2bf_rn(s.w - bf2f(h.w));
    ((us4*)xh)[i] = h;
    ((us4*)xl)[i] = l;

    float sq = s.x * s.x + s.y * s.y + s.z * s.z + s.w * s.w;
    #pragma unroll
    for (int off = 32; off > 0; off >>= 1) sq += __shfl_down(sq, off, 64);
    __shared__ float wsum[4];
    const int lane = threadIdx.x & 63, wwid = threadIdx.x >> 6;
    if (lane == 0) wsum[wwid] = sq;
    __syncthreads();
    if (threadIdx.x == 0)
        xn[b] = sqrtf(wsum[0] + wsum[1] + wsum[2] + wsum[3]);
}

// ---------------------------------------------------------------------------
// Fused reduce(2 partials) + cosine scale + top-4 + softmax weights.
// NOW 256 threads: 4 waves each scan a quarter of M (4 iters instead of 16),
// butterfly within wave, LDS merge of 16 candidates by thread 0.
// Top-4 under lexicographic (value, -index) order is a pure function of the
// multiset -> partition order cannot change the result (bit-identical).
// ---------------------------------------------------------------------------
__device__ inline bool tk_better(float x, int ix, float y, int iy) {
    return (x > y) || (x == y && ix < iy);
}
__device__ inline void tk_insert(float (&v)[4], int (&id)[4], float x, int m) {
    if (tk_better(x, m, v[3], id[3])) {
        v[3] = x; id[3] = m;
        if (tk_better(v[3], id[3], v[2], id[2])) {
            float tv = v[2]; int ti = id[2]; v[2] = v[3]; id[2] = id[3]; v[3] = tv; id[3] = ti;
            if (tk_better(v[2], id[2], v[1], id[1])) {
                tv = v[1]; ti = id[1]; v[1] = v[2]; id[1] = id[2]; v[2] = tv; id[2] = ti;
                if (tk_better(v[1], id[1], v[0], id[0])) {
                    tv = v[0]; ti = id[0]; v[0] = v[1]; id[0] = id[1]; v[1] = tv; id[1] = ti;
                }
            }
        }
    }
}
__global__ __launch_bounds__(256)
void topk_scale_kernel(const float* __restrict__ Cp2, const float* __restrict__ xn,
                       const float* __restrict__ kn,
                       int* __restrict__ topi, float* __restrict__ topw)
{
    const int b = blockIdx.x, t = threadIdx.x;
    const int lane = t & 63, wid = t >> 6;
    const float sb = 1.f / fmaxf(xn[b], EPSF);
    const float* r0 = Cp2 + (size_t)b * MDIM;
    const float* r1 = Cp2 + (size_t)BDIM * MDIM + (size_t)b * MDIM;

    float v[4] = {-INFINITY, -INFINITY, -INFINITY, -INFINITY};
    int id[4] = {-1, -1, -1, -1};
    #pragma unroll
    for (int j = 0; j < MDIM / 256; ++j) {
        int m = wid * 256 + j * 64 + lane;
        float s = (r0[m] + r1[m]) * sb / fmaxf(kn[m], EPSF);
        tk_insert(v, id, s, m);
    }
    for (int off = 32; off >= 1; off >>= 1) {
        float pv[4]; int pi[4];
        #pragma unroll
        for (int q = 0; q < 4; ++q) {
            pv[q] = __shfl_xor(v[q], off, 64);
            pi[q] = __shfl_xor(id[q], off, 64);
        }
        #pragma unroll
        for (int q = 0; q < 4; ++q) tk_insert(v, id, pv[q], pi[q]);
    }

    __shared__ float sv[4][4];
    __shared__ int   si[4][4];
    if (lane == 0) {
        #pragma unroll
        for (int q = 0; q < 4; ++q) { sv[wid][q] = v[q]; si[wid][q] = id[q]; }
    }
    __syncthreads();
    if (t == 0) {
        float fv[4] = {-INFINITY, -INFINITY, -INFINITY, -INFINITY};
        int   fi[4] = {-1, -1, -1, -1};
        #pragma unroll
        for (int w = 0; w < 4; ++w)
            #pragma unroll
            for (int q = 0; q < 4; ++q)
                tk_insert(fv, fi, sv[w][q], si[w][q]);

        const float mx = fmaxf(fmaxf(fv[0], fv[1]), fmaxf(fv[2], fv[3]));
        const float e0 = expf(fv[0] - mx), e1 = expf(fv[1] - mx);
        const float e2 = expf(fv[2] - mx), e3 = expf(fv[3] - mx);
        const float inv = 1.f / (e0 + e1 + e2 + e3);
        topw[b * 4 + 0] = e0 * inv; topw[b * 4 + 1] = e1 * inv;
        topw[b * 4 + 2] = e2 * inv; topw[b * 4 + 3] = e3 * inv;
        #pragma unroll
        for (int q = 0; q < 4; ++q) topi[b * 4 + q] = fi[q];
    }
}

// ---------------------------------------------------------------------------
// Gather + weighted sum. (l, b)-major + non-temporal stores; fully unrolled
// so all 16 stream loads are in flight together.
// ---------------------------------------------------------------------------
__global__ __launch_bounds__(256)
void gather_out_kernel(const float* __restrict__ pm, const int* __restrict__ topi,
                       const float* __restrict__ topw, float* __restrict__ out)
{
    const int bl = blockIdx.x;
    const int b = bl & (BDIM - 1);   // (l, b)-major
    const int l = bl >> 9;

    const int j0 = topi[b * 4 + 0], j1 = topi[b * 4 + 1], j2 = topi[b * 4 + 2], j3 = topi[b * 4 + 3];
    const float w0 = topw[b * 4 + 0], w1 = topw[b * 4 + 1], w2 = topw[b * 4 + 2], w3 = topw[b * 4 + 3];

    const f32x4* p0 = (const f32x4*)(pm + ((size_t)j0 * LDIM + l) * EDIM);
    const f32x4* p1 = (const f32x4*)(pm + ((size_t)j1 * LDIM + l) * EDIM);
    const f32x4* p2 = (const f32x4*)(pm + ((size_t)j2 * LDIM + l) * EDIM);
    const f32x4* p3 = (const f32x4*)(pm + ((size_t)j3 * LDIM + l) * EDIM);
    f32x4* o = (f32x4*)(out + ((size_t)b * LDIM + l) * EDIM);

    #pragma unroll
    for (int it = 0; it < EDIM / 4 / 256; ++it) {
        const int c = it * 256 + threadIdx.x;
        f32x4 a = p0[c], bb = p1[c], cc = p2[c], dd = p3[c];
        f32x4 r = w0 * a + w1 * bb + w2 * cc + w3 * dd;
        __builtin_nontemporal_store(r, &o[c]);
    }
}

extern "C" void kernel_launch(void* const* d_in, const int* in_sizes, int n_in,
                              void* d_out, int out_size, void* d_ws, size_t ws_size,
                              hipStream_t stream)
{
    const float* x_query = (const float*)d_in[0];      // [B, E]
    const float* W_proj  = (const float*)d_in[1];      // [K, E]
    const float* pm      = (const float*)d_in[2];      // [M, L, E]
    const float* pkeys   = (const float*)d_in[3];      // [M, K]
    float* out = (float*)d_out;                        // [B, L, E]

    // workspace layout
    char* w = (char*)d_ws;
    ushort* xq_h = (ushort*)w; w += (size_t)BDIM * EDIM * 2;
    ushort* xq_l = (ushort*)w; w += (size_t)BDIM * EDIM * 2;
    ushort* wp_h = (ushort*)w; w += (size_t)KDIM * EDIM * 2;
    ushort* wp_l = (ushort*)w; w += (size_t)KDIM * EDIM * 2;
    ushort* pk_h = (ushort*)w; w += (size_t)MDIM * KDIM * 2;
    ushort* pk_l = (ushort*)w; w += (size_t)MDIM * KDIM * 2;
    ushort* xp_h = (ushort*)w; w += (size_t)BDIM * KDIM * 2;
    ushort* xp_l = (ushort*)w; w += (size_t)BDIM * KDIM * 2;
    float* Cp1  = (float*)w; w += (size_t)4 * BDIM * KDIM * 4;
    float* Cp2  = (float*)w; w += (size_t)2 * BDIM * MDIM * 4;
    float* xn   = (float*)w; w += BDIM * 4;
    float* kn   = (float*)w; w += MDIM * 4;
    float* topw = (float*)w; w += BDIM * TOPK * 4;
    int*   topi = (int*)w;   w += BDIM * TOPK * 4;

    // 1. split all three fp32 inputs to hi/lo bf16 + pkeys row norms
    split_all_kernel<<<1792, 256, 0, stream>>>(
        x_query, W_proj, pkeys, xq_h, xq_l, wp_h, wp_l, pk_h, pk_l, kn);

    // 2. x_proj partials (64x128 tile, dbuf LDS, split-K=4)
    gemm1_kernel<<<dim3(KDIM / 128, BDIM / 64, 4), 256, 0, stream>>>(
        xq_h, xq_l, wp_h, wp_l, Cp1);

    // 3. fused reduce + rownorm + split of x_proj (one block per row)
    reduce_split_norm_kernel<<<BDIM, 256, 0, stream>>>(Cp1, xp_h, xp_l, xn);

    // 4. sim partials (64x64 tile, dbuf LDS, split-K=2)
    gemm2_kernel<<<dim3(MDIM / 64, BDIM / 64, 2), 256, 0, stream>>>(
        xp_h, xp_l, pk_h, pk_l, Cp2);

    // 5. fused reduce + cosine scale + top-4 + softmax weights (4 waves/row)
    topk_scale_kernel<<<BDIM, 256, 0, stream>>>(Cp2, xn, kn, topi, topw);

    // 6. gather + weighted sum -> out [512,32,4096]
    gather_out_kernel<<<BDIM * LDIM, 256, 0, stream>>>(pm, topi, topw, out);
}

// Round 9
// 232.744 us; speedup vs baseline: 1.0671x; 1.0081x over previous
//
#include <hip/hip_runtime.h>
#include <math.h>

#define BDIM 512
#define EDIM 4096
#define KDIM 1024
#define MDIM 1024
#define LDIM 32
#define TOPK 4
#define EPSF 1e-12f

typedef __attribute__((ext_vector_type(8))) short short8;
typedef __attribute__((ext_vector_type(4))) float f32x4;

struct us4 { ushort x, y, z, w; };

__device__ inline ushort f2bf_rn(float x) {
    union { float f; unsigned u; } v; v.f = x;
    unsigned r = (v.u + 0x7FFF + ((v.u >> 16) & 1)) >> 16;
    return (ushort)r;
}
__device__ inline float bf2f(ushort h) {
    union { unsigned u; float f; } v; v.u = ((unsigned)h) << 16;
    return v.f;
}
// fp32x8 -> (hi, lo) bf16x8; identical bit pattern to the old split_all pass.
__device__ inline void split8(const float4& v0, const float4& v1,
                              short8& h, short8& l)
{
    float f[8] = {v0.x, v0.y, v0.z, v0.w, v1.x, v1.y, v1.z, v1.w};
    #pragma unroll
    for (int e = 0; e < 8; ++e) {
        ushort hh = f2bf_rn(f[e]);
        h[e] = (short)hh;
        l[e] = (short)f2bf_rn(f[e] - bf2f(hh));
    }
}

// ---------------------------------------------------------------------------
// GEMM1: x_proj partials directly from fp32 x_query [512][4096] and W_proj
// [1024][4096]. hi/lo bf16 split happens IN-REGISTER before the ds_write:
// hi+lo (4 B/elem) == fp32 (4 B/elem), so staging bytes are unchanged vs the
// pre-split version (96 B/thread/k-step) and the 58 MB split_all pass dies.
// split8 bits == split_all bits -> LDS content -> Cp1 all bit-identical.
// 64(M) x 128(N) tile, BK=32, 4 waves each 32x64 (2x4 16x16x32 frags),
// LDS double-buffered (1 barrier/k-step), split-K=4 -> Cp1[z][512][1024].
// ---------------------------------------------------------------------------
__global__ __launch_bounds__(256)
void gemm1_kernel(const float* __restrict__ A, const float* __restrict__ B,
                  float* __restrict__ Cp)
{
    __shared__ ushort ldsA[2][2][64][40];    // [buf][hi/lo][row][col]
    __shared__ ushort ldsB[2][2][128][40];

    const int t  = threadIdx.x;
    const int bn = blockIdx.x, bm = blockIdx.y, kz = blockIdx.z;
    const int srow = t >> 2, sg = t & 3;
    const int Kc = EDIM / 4;                 // 1024

    const size_t aoff  = (size_t)(bm * 64 + srow) * EDIM + kz * Kc + sg * 8;
    const size_t boff0 = (size_t)(bn * 128 + srow) * EDIM + kz * Kc + sg * 8;
    const size_t boff1 = (size_t)(bn * 128 + 64 + srow) * EDIM + kz * Kc + sg * 8;

    const int lane = t & 63, wid = t >> 6;
    const int wr = wid >> 1, wc = wid & 1;
    const int fr = lane & 15, fg = lane >> 4;

    f32x4 acc[2][4];
    #pragma unroll
    for (int i = 0; i < 2; ++i)
        #pragma unroll
        for (int j = 0; j < 4; ++j)
            acc[i][j] = (f32x4){0.f, 0.f, 0.f, 0.f};

    float4 a0 = *(const float4*)(A + aoff),  a1 = *(const float4*)(A + aoff + 4);
    float4 b00 = *(const float4*)(B + boff0), b01 = *(const float4*)(B + boff0 + 4);
    float4 b10 = *(const float4*)(B + boff1), b11 = *(const float4*)(B + boff1 + 4);

    {
        short8 hs, ls;
        split8(a0, a1, hs, ls);
        *(short8*)(&ldsA[0][0][srow][sg * 8]) = hs;
        *(short8*)(&ldsA[0][1][srow][sg * 8]) = ls;
        split8(b00, b01, hs, ls);
        *(short8*)(&ldsB[0][0][srow][sg * 8]) = hs;
        *(short8*)(&ldsB[0][1][srow][sg * 8]) = ls;
        split8(b10, b11, hs, ls);
        *(short8*)(&ldsB[0][0][64 + srow][sg * 8]) = hs;
        *(short8*)(&ldsB[0][1][64 + srow][sg * 8]) = ls;
    }

    int p = 0;
    for (int k0 = 0; k0 < Kc; k0 += 32) {
        const bool more = (k0 + 32 < Kc);
        if (more) {                          // issue next-chunk global loads
            a0  = *(const float4*)(A + aoff + k0 + 32);
            a1  = *(const float4*)(A + aoff + k0 + 36);
            b00 = *(const float4*)(B + boff0 + k0 + 32);
            b01 = *(const float4*)(B + boff0 + k0 + 36);
            b10 = *(const float4*)(B + boff1 + k0 + 32);
            b11 = *(const float4*)(B + boff1 + k0 + 36);
        }
        __syncthreads();                     // buf[p] writes visible

        short8 ah[2], al[2], bh[4], bl[4];
        #pragma unroll
        for (int i = 0; i < 2; ++i) {
            ah[i] = *(const short8*)(&ldsA[p][0][wr * 32 + i * 16 + fr][fg * 8]);
            al[i] = *(const short8*)(&ldsA[p][1][wr * 32 + i * 16 + fr][fg * 8]);
        }
        #pragma unroll
        for (int j = 0; j < 4; ++j) {
            bh[j] = *(const short8*)(&ldsB[p][0][wc * 64 + j * 16 + fr][fg * 8]);
            bl[j] = *(const short8*)(&ldsB[p][1][wc * 64 + j * 16 + fr][fg * 8]);
        }
        #pragma unroll
        for (int i = 0; i < 2; ++i)
            #pragma unroll
            for (int j = 0; j < 4; ++j) {
                acc[i][j] = __builtin_amdgcn_mfma_f32_16x16x32_bf16(ah[i], bh[j], acc[i][j], 0, 0, 0);
                acc[i][j] = __builtin_amdgcn_mfma_f32_16x16x32_bf16(ah[i], bl[j], acc[i][j], 0, 0, 0);
                acc[i][j] = __builtin_amdgcn_mfma_f32_16x16x32_bf16(al[i], bh[j], acc[i][j], 0, 0, 0);
            }

        if (more) {                          // split + write next chunk to buf[p^1]
            short8 hs, ls;
            split8(a0, a1, hs, ls);
            *(short8*)(&ldsA[p ^ 1][0][srow][sg * 8]) = hs;
            *(short8*)(&ldsA[p ^ 1][1][srow][sg * 8]) = ls;
            split8(b00, b01, hs, ls);
            *(short8*)(&ldsB[p ^ 1][0][srow][sg * 8]) = hs;
            *(short8*)(&ldsB[p ^ 1][1][srow][sg * 8]) = ls;
            split8(b10, b11, hs, ls);
            *(short8*)(&ldsB[p ^ 1][0][64 + srow][sg * 8]) = hs;
            *(short8*)(&ldsB[p ^ 1][1][64 + srow][sg * 8]) = ls;
        }
        p ^= 1;
    }

    float* Cz = Cp + (size_t)kz * BDIM * KDIM;
    #pragma unroll
    for (int i = 0; i < 2; ++i)
        #pragma unroll
        for (int j = 0; j < 4; ++j)
            #pragma unroll
            for (int q = 0; q < 4; ++q) {
                int orow = bm * 64 + wr * 32 + i * 16 + (lane >> 4) * 4 + q;
                int ocol = bn * 128 + wc * 64 + j * 16 + (lane & 15);
                Cz[(size_t)orow * KDIM + ocol] = acc[i][j][q];
            }
}

// ---------------------------------------------------------------------------
// Fused reductions: blocks [0,512) = reduce split-K=4 partials of x_proj row
// + L2-norm + hi/lo split (verbatim round-8 path, bit-identical). Blocks
// [512,1536) = kn for one pkeys row each (reduction order verbatim from the
// verified norms kernel, bit-identical).
// ---------------------------------------------------------------------------
__global__ __launch_bounds__(256)
void reduce_split_norm_kernel(const float* __restrict__ Cp,
                              const float* __restrict__ PK,
                              ushort* __restrict__ xh, ushort* __restrict__ xl,
                              float* __restrict__ xn, float* __restrict__ kn)
{
    const int blk = blockIdx.x, t = threadIdx.x;
    float sq;
    if (blk < BDIM) {
        const int b = blk;
        const int i = b * 256 + t;
        const int n4 = BDIM * KDIM / 4;

        float4 s = ((const float4*)Cp)[i];
        #pragma unroll
        for (int z = 1; z < 4; ++z) {
            float4 v = ((const float4*)Cp)[(size_t)z * n4 + i];
            s.x += v.x; s.y += v.y; s.z += v.z; s.w += v.w;
        }

        us4 h, l;
        h.x = f2bf_rn(s.x); l.x = f2bf_rn(s.x - bf2f(h.x));
        h.y = f2bf_rn(s.y); l.y = f2bf_rn(s.y - bf2f(h.y));
        h.z = f2bf_rn(s.z); l.z = f2bf_rn(s.z - bf2f(h.z));
        h.w = f2bf_rn(s.w); l.w = f2bf_rn(s.w - bf2f(h.w));
        ((us4*)xh)[i] = h;
        ((us4*)xl)[i] = l;

        sq = s.x * s.x + s.y * s.y + s.z * s.z + s.w * s.w;
    } else {
        const int m = blk - BDIM;
        float4 v = *(const float4*)(PK + (size_t)m * KDIM + t * 4);
        sq = v.x * v.x + v.y * v.y + v.z * v.z + v.w * v.w;
    }
    #pragma unroll
    for (int off = 32; off > 0; off >>= 1) sq += __shfl_down(sq, off, 64);
    __shared__ float wsum[4];
    const int lane = t & 63, wwid = t >> 6;
    if (lane == 0) wsum[wwid] = sq;
    __syncthreads();
    if (t == 0) {
        float r = sqrtf(wsum[0] + wsum[1] + wsum[2] + wsum[3]);
        if (blk < BDIM) xn[blk] = r; else kn[blk - BDIM] = r;
    }
}

// ---------------------------------------------------------------------------
// GEMM2 (sim partials): A = pre-split xp (from reduce kernel); B = pkeys fp32
// split in-register (same bytes as the h/l pair; bits identical to pk_h/pk_l).
// 64x64 tile, dbuf LDS, split-K=2 -> Cp2[z][512][1024]. Bit-identical.
// ---------------------------------------------------------------------------
__global__ __launch_bounds__(256)
void gemm2_kernel(const ushort* __restrict__ Ah, const ushort* __restrict__ Al,
                  const float* __restrict__ PK, float* __restrict__ Cp)
{
    __shared__ ushort lds[2][4][64][40];     // [buf][Ah/Al/Bh/Bl][row][col]

    const int t  = threadIdx.x;
    const int bn = blockIdx.x, bm = blockIdx.y, kz = blockIdx.z;
    const int srow = t >> 2, sg = t & 3;
    const int Kc = KDIM / 2;                 // 512

    const size_t aoff = (size_t)(bm * 64 + srow) * KDIM + kz * Kc + sg * 8;
    const size_t boff = (size_t)(bn * 64 + srow) * KDIM + kz * Kc + sg * 8;

    const int lane = t & 63, wid = t >> 6;
    const int wr = wid >> 1, wc = wid & 1;
    const int fr = lane & 15, fg = lane >> 4;

    f32x4 acc[2][2];
    #pragma unroll
    for (int i = 0; i < 2; ++i)
        #pragma unroll
        for (int j = 0; j < 2; ++j)
            acc[i][j] = (f32x4){0.f, 0.f, 0.f, 0.f};

    short8 pA0 = *(const short8*)(Ah + aoff);
    short8 pA1 = *(const short8*)(Al + aoff);
    float4 pb0 = *(const float4*)(PK + boff);
    float4 pb1 = *(const float4*)(PK + boff + 4);

    {
        short8 hs, ls;
        split8(pb0, pb1, hs, ls);
        *(short8*)(&lds[0][0][srow][sg * 8]) = pA0;
        *(short8*)(&lds[0][1][srow][sg * 8]) = pA1;
        *(short8*)(&lds[0][2][srow][sg * 8]) = hs;
        *(short8*)(&lds[0][3][srow][sg * 8]) = ls;
    }

    int p = 0;
    for (int k0 = 0; k0 < Kc; k0 += 32) {
        const bool more = (k0 + 32 < Kc);
        if (more) {
            pA0 = *(const short8*)(Ah + aoff + k0 + 32);
            pA1 = *(const short8*)(Al + aoff + k0 + 32);
            pb0 = *(const float4*)(PK + boff + k0 + 32);
            pb1 = *(const float4*)(PK + boff + k0 + 36);
        }
        __syncthreads();

        short8 ah[2], al[2], bh[2], bl[2];
        #pragma unroll
        for (int i = 0; i < 2; ++i) {
            ah[i] = *(const short8*)(&lds[p][0][wr * 32 + i * 16 + fr][fg * 8]);
            al[i] = *(const short8*)(&lds[p][1][wr * 32 + i * 16 + fr][fg * 8]);
            bh[i] = *(const short8*)(&lds[p][2][wc * 32 + i * 16 + fr][fg * 8]);
            bl[i] = *(const short8*)(&lds[p][3][wc * 32 + i * 16 + fr][fg * 8]);
        }
        #pragma unroll
        for (int i = 0; i < 2; ++i)
            #pragma unroll
            for (int j = 0; j < 2; ++j) {
                acc[i][j] = __builtin_amdgcn_mfma_f32_16x16x32_bf16(ah[i], bh[j], acc[i][j], 0, 0, 0);
                acc[i][j] = __builtin_amdgcn_mfma_f32_16x16x32_bf16(ah[i], bl[j], acc[i][j], 0, 0, 0);
                acc[i][j] = __builtin_amdgcn_mfma_f32_16x16x32_bf16(al[i], bh[j], acc[i][j], 0, 0, 0);
            }

        if (more) {
            short8 hs, ls;
            split8(pb0, pb1, hs, ls);
            *(short8*)(&lds[p ^ 1][0][srow][sg * 8]) = pA0;
            *(short8*)(&lds[p ^ 1][1][srow][sg * 8]) = pA1;
            *(short8*)(&lds[p ^ 1][2][srow][sg * 8]) = hs;
            *(short8*)(&lds[p ^ 1][3][srow][sg * 8]) = ls;
        }
        p ^= 1;
    }

    float* Cz = Cp + (size_t)kz * BDIM * MDIM;
    #pragma unroll
    for (int i = 0; i < 2; ++i)
        #pragma unroll
        for (int j = 0; j < 2; ++j)
            #pragma unroll
            for (int q = 0; q < 4; ++q) {
                int orow = bm * 64 + wr * 32 + i * 16 + (lane >> 4) * 4 + q;
                int ocol = bn * 64 + wc * 32 + j * 16 + (lane & 15);
                Cz[(size_t)orow * MDIM + ocol] = acc[i][j][q];
            }
}

// ---------------------------------------------------------------------------
// Fused reduce(2 partials) + cosine scale + top-4 + softmax weights.
// 256 threads: 4 waves scan a quarter of M each; LDS merge. Bit-identical
// (top-4 under (value,-index) lexicographic order is partition-invariant).
// ---------------------------------------------------------------------------
__device__ inline bool tk_better(float x, int ix, float y, int iy) {
    return (x > y) || (x == y && ix < iy);
}
__device__ inline void tk_insert(float (&v)[4], int (&id)[4], float x, int m) {
    if (tk_better(x, m, v[3], id[3])) {
        v[3] = x; id[3] = m;
        if (tk_better(v[3], id[3], v[2], id[2])) {
            float tv = v[2]; int ti = id[2]; v[2] = v[3]; id[2] = id[3]; v[3] = tv; id[3] = ti;
            if (tk_better(v[2], id[2], v[1], id[1])) {
                tv = v[1]; ti = id[1]; v[1] = v[2]; id[1] = id[2]; v[2] = tv; id[2] = ti;
                if (tk_better(v[1], id[1], v[0], id[0])) {
                    tv = v[0]; ti = id[0]; v[0] = v[1]; id[0] = id[1]; v[1] = tv; id[1] = ti;
                }
            }
        }
    }
}
__global__ __launch_bounds__(256)
void topk_scale_kernel(const float* __restrict__ Cp2, const float* __restrict__ xn,
                       const float* __restrict__ kn,
                       int* __restrict__ topi, float* __restrict__ topw)
{
    const int b = blockIdx.x, t = threadIdx.x;
    const int lane = t & 63, wid = t >> 6;
    const float sb = 1.f / fmaxf(xn[b], EPSF);
    const float* r0 = Cp2 + (size_t)b * MDIM;
    const float* r1 = Cp2 + (size_t)BDIM * MDIM + (size_t)b * MDIM;

    float v[4] = {-INFINITY, -INFINITY, -INFINITY, -INFINITY};
    int id[4] = {-1, -1, -1, -1};
    #pragma unroll
    for (int j = 0; j < MDIM / 256; ++j) {
        int m = wid * 256 + j * 64 + lane;
        float s = (r0[m] + r1[m]) * sb / fmaxf(kn[m], EPSF);
        tk_insert(v, id, s, m);
    }
    for (int off = 32; off >= 1; off >>= 1) {
        float pv[4]; int pi[4];
        #pragma unroll
        for (int q = 0; q < 4; ++q) {
            pv[q] = __shfl_xor(v[q], off, 64);
            pi[q] = __shfl_xor(id[q], off, 64);
        }
        #pragma unroll
        for (int q = 0; q < 4; ++q) tk_insert(v, id, pv[q], pi[q]);
    }

    __shared__ float sv[4][4];
    __shared__ int   si[4][4];
    if (lane == 0) {
        #pragma unroll
        for (int q = 0; q < 4; ++q) { sv[wid][q] = v[q]; si[wid][q] = id[q]; }
    }
    __syncthreads();
    if (t == 0) {
        float fv[4] = {-INFINITY, -INFINITY, -INFINITY, -INFINITY};
        int   fi[4] = {-1, -1, -1, -1};
        #pragma unroll
        for (int w = 0; w < 4; ++w)
            #pragma unroll
            for (int q = 0; q < 4; ++q)
                tk_insert(fv, fi, sv[w][q], si[w][q]);

        const float mx = fmaxf(fmaxf(fv[0], fv[1]), fmaxf(fv[2], fv[3]));
        const float e0 = expf(fv[0] - mx), e1 = expf(fv[1] - mx);
        const float e2 = expf(fv[2] - mx), e3 = expf(fv[3] - mx);
        const float inv = 1.f / (e0 + e1 + e2 + e3);
        topw[b * 4 + 0] = e0 * inv; topw[b * 4 + 1] = e1 * inv;
        topw[b * 4 + 2] = e2 * inv; topw[b * 4 + 3] = e3 * inv;
        #pragma unroll
        for (int q = 0; q < 4; ++q) topi[b * 4 + q] = fi[q];
    }
}

// ---------------------------------------------------------------------------
// Gather + weighted sum. (l, b)-major + non-temporal stores; fully unrolled
// so all 16 stream loads are in flight. Unchanged from round 8.
// ---------------------------------------------------------------------------
__global__ __launch_bounds__(256)
void gather_out_kernel(const float* __restrict__ pm, const int* __restrict__ topi,
                       const float* __restrict__ topw, float* __restrict__ out)
{
    const int bl = blockIdx.x;
    const int b = bl & (BDIM - 1);   // (l, b)-major
    const int l = bl >> 9;

    const int j0 = topi[b * 4 + 0], j1 = topi[b * 4 + 1], j2 = topi[b * 4 + 2], j3 = topi[b * 4 + 3];
    const float w0 = topw[b * 4 + 0], w1 = topw[b * 4 + 1], w2 = topw[b * 4 + 2], w3 = topw[b * 4 + 3];

    const f32x4* p0 = (const f32x4*)(pm + ((size_t)j0 * LDIM + l) * EDIM);
    const f32x4* p1 = (const f32x4*)(pm + ((size_t)j1 * LDIM + l) * EDIM);
    const f32x4* p2 = (const f32x4*)(pm + ((size_t)j2 * LDIM + l) * EDIM);
    const f32x4* p3 = (const f32x4*)(pm + ((size_t)j3 * LDIM + l) * EDIM);
    f32x4* o = (f32x4*)(out + ((size_t)b * LDIM + l) * EDIM);

    #pragma unroll
    for (int it = 0; it < EDIM / 4 / 256; ++it) {
        const int c = it * 256 + threadIdx.x;
        f32x4 a = p0[c], bb = p1[c], cc = p2[c], dd = p3[c];
        f32x4 r = w0 * a + w1 * bb + w2 * cc + w3 * dd;
        __builtin_nontemporal_store(r, &o[c]);
    }
}

extern "C" void kernel_launch(void* const* d_in, const int* in_sizes, int n_in,
                              void* d_out, int out_size, void* d_ws, size_t ws_size,
                              hipStream_t stream)
{
    const float* x_query = (const float*)d_in[0];      // [B, E]
    const float* W_proj  = (const float*)d_in[1];      // [K, E]
    const float* pm      = (const float*)d_in[2];      // [M, L, E]
    const float* pkeys   = (const float*)d_in[3];      // [M, K]
    float* out = (float*)d_out;                        // [B, L, E]

    // workspace layout
    char* w = (char*)d_ws;
    ushort* xp_h = (ushort*)w; w += (size_t)BDIM * KDIM * 2;
    ushort* xp_l = (ushort*)w; w += (size_t)BDIM * KDIM * 2;
    float* Cp1  = (float*)w; w += (size_t)4 * BDIM * KDIM * 4;   // 8 MB
    float* Cp2  = (float*)w; w += (size_t)2 * BDIM * MDIM * 4;   // 4 MB
    float* xn   = (float*)w; w += BDIM * 4;
    float* kn   = (float*)w; w += MDIM * 4;
    float* topw = (float*)w; w += BDIM * TOPK * 4;
    int*   topi = (int*)w;   w += BDIM * TOPK * 4;

    // 1. x_proj partials (fp32 inputs, in-register split, 64x128 dbuf, K=4)
    gemm1_kernel<<<dim3(KDIM / 128, BDIM / 64, 4), 256, 0, stream>>>(
        x_query, W_proj, Cp1);

    // 2. reduce + rownorm + split of x_proj  +  kn of pkeys rows
    reduce_split_norm_kernel<<<BDIM + MDIM, 256, 0, stream>>>(
        Cp1, pkeys, xp_h, xp_l, xn, kn);

    // 3. sim partials (A pre-split, B=pkeys fp32 in-register split, dbuf, K=2)
    gemm2_kernel<<<dim3(MDIM / 64, BDIM / 64, 2), 256, 0, stream>>>(
        xp_h, xp_l, pkeys, Cp2);

    // 4. reduce + cosine scale + top-4 + softmax weights (4 waves/row)
    topk_scale_kernel<<<BDIM, 256, 0, stream>>>(Cp2, xn, kn, topi, topw);

    // 5. gather + weighted sum -> out [512,32,4096]
    gather_out_kernel<<<BDIM * LDIM, 256, 0, stream>>>(pm, topi, topw, out);
}